// Round 15
// baseline (152.869 us; speedup 1.0000x reference)
//
#include <hip/hip_runtime.h>
#include <hip/hip_bf16.h>
#include <cstdint>

#define DIMC 1024
#define HEADS 16
#define DHH 64
#define SEQ 4096
#define LATENT 1024
#define HISTC 3072
#define BATCH 2

typedef __attribute__((ext_vector_type(8))) __bf16 bf16x8;
typedef __attribute__((ext_vector_type(4))) float f32x4;
typedef __attribute__((ext_vector_type(16))) float f32x16;

// ---------------- fused prep: x->bf16, 3 weights->bf16, RoPE cos/sin table ----
__global__ void k_prep(const float* __restrict__ x, const float* __restrict__ Wq,
                       const float* __restrict__ Wkv, const float* __restrict__ Wo,
                       __bf16* __restrict__ x16, __bf16* __restrict__ wq16,
                       __bf16* __restrict__ wkv16, __bf16* __restrict__ wo16,
                       float2* __restrict__ cs) {
  int bidx = blockIdx.x;
  if (bidx < 2048) {
    int base = bidx * 256 + threadIdx.x;
#pragma unroll
    for (int k = 0; k < 4; ++k) {
      int i = base + k * 524288;
      float4 v = reinterpret_cast<const float4*>(x)[i];
      union { __bf16 h[4]; uint64_t u; } p;
      p.h[0] = (__bf16)v.x; p.h[1] = (__bf16)v.y;
      p.h[2] = (__bf16)v.z; p.h[3] = (__bf16)v.w;
      reinterpret_cast<uint64_t*>(x16)[i] = p.u;
    }
  } else if (bidx < 3584) {
    int id = bidx - 2048;
    const float* src; __bf16* dst;
    if (id < 512) { src = Wq; dst = wq16; }
    else if (id < 1024) { src = Wkv; dst = wkv16; id -= 512; }
    else { src = Wo; dst = wo16; id -= 1024; }
#pragma unroll
    for (int k = 0; k < 2; ++k) {
      int idx = id * 512 + k * 256 + threadIdx.x;
      float4 v = reinterpret_cast<const float4*>(src)[idx];
      union { __bf16 h[4]; uint64_t u; } p;
      p.h[0] = (__bf16)v.x; p.h[1] = (__bf16)v.y;
      p.h[2] = (__bf16)v.z; p.h[3] = (__bf16)v.w;
      reinterpret_cast<uint64_t*>(dst)[idx] = p.u;
    }
  } else {
    int idx = (bidx - 3584) * 256 + threadIdx.x;   // 4096*32 entries
    int pos = idx >> 5, f = idx & 31;
    float invf = exp2f(-(float)f * 0.41524101186f);  // log2(10000)/32
    float s, c;
    sincosf((float)pos * invf, &s, &c);
    cs[idx] = make_float2(c, s);
  }
}

// ---------------- async global->LDS 16B ----------------
__device__ __forceinline__ void gload16(void* lds, const void* g) {
  __builtin_amdgcn_global_load_lds(
      (const __attribute__((address_space(1))) unsigned int*)g,
      (__attribute__((address_space(3))) unsigned int*)lds, 16, 0, 0);
}

// ---------------- plain GEMM (o-proj): C = A @ Bw^T + bias ----
template<int BIAS>
__launch_bounds__(256)
__global__ void k_gemm(const __bf16* __restrict__ A, const __bf16* __restrict__ Bw,
                       float* __restrict__ C, const float* __restrict__ bias,
                       int M, int N, int K) {
  __shared__ __align__(16) char lds[16384];
  const int t = threadIdx.x;
  const int l = t & 63, w = t >> 6;
  const int wr = w >> 1, wc = w & 1;
  const int mblocks = M >> 7;
  const int m0 = (blockIdx.x % mblocks) * 128, n0 = (blockIdx.x / mblocks) * 128;
  const int lrow = l & 15, lk = l >> 4;
  f32x4 acc[4][4] = {};

  for (int k0 = 0; k0 < K; k0 += 32) {
    if (k0) __syncthreads();
#pragma unroll
    for (int i = 0; i < 2; ++i) {
      int c = i * 256 + t;
      int row = c >> 2, kc = c & 3;
      gload16(lds + c * 16, A + (size_t)(m0 + row) * K + k0 + kc * 8);
      gload16(lds + 8192 + c * 16, Bw + (size_t)(n0 + row) * K + k0 + kc * 8);
    }
    __syncthreads();
    bf16x8 af[4], bfr[4];
#pragma unroll
    for (int m = 0; m < 4; ++m)
      af[m] = *reinterpret_cast<const bf16x8*>(lds + (wr * 64 + m * 16 + lrow) * 64 + lk * 16);
#pragma unroll
    for (int n = 0; n < 4; ++n)
      bfr[n] = *reinterpret_cast<const bf16x8*>(lds + 8192 + (wc * 64 + n * 16 + lrow) * 64 + lk * 16);
#pragma unroll
    for (int m = 0; m < 4; ++m)
#pragma unroll
      for (int n = 0; n < 4; ++n)
        acc[m][n] = __builtin_amdgcn_mfma_f32_16x16x32_bf16(af[m], bfr[n], acc[m][n], 0, 0, 0);
  }

#pragma unroll
  for (int m = 0; m < 4; ++m)
#pragma unroll
    for (int n = 0; n < 4; ++n)
#pragma unroll
      for (int r = 0; r < 4; ++r) {
        int row = m0 + wr * 64 + m * 16 + (l >> 4) * 4 + r;
        int col = n0 + wc * 64 + n * 16 + (l & 15);
        float v = acc[m][n][r];
        if (BIAS) v += bias[col];
        C[(size_t)row * N + col] = v;
      }
}

// ---------------- fused QKV GEMM: kv-proj(+RoPE+LN) and q-proj(+RoPE+scale) ----
__launch_bounds__(256)
__global__ void k_gemmqkv(const __bf16* __restrict__ x16,
                          const __bf16* __restrict__ wkv16,
                          const __bf16* __restrict__ wq16,
                          __bf16* __restrict__ kvn, __bf16* __restrict__ kvnT,
                          __bf16* __restrict__ qb,
                          const float* __restrict__ gamma,
                          const float* __restrict__ beta,
                          const float2* __restrict__ cstab) {
  __shared__ __align__(16) char lds[16384];
  const int t = threadIdx.x, l = t & 63, w = t >> 6;
  const int wr = w >> 1, wc = w & 1;
  const int by = blockIdx.x % 80;
  const bool isq = by >= 64;
  const int m0 = (isq ? (by - 64) : by) * 128;
  const int n0 = (blockIdx.x / 80) * 128;
  const __bf16* Bw = isq ? wq16 : wkv16;
  const int lrow = l & 15, lk = l >> 4;
  f32x4 acc[4][4] = {};

  for (int k0 = 0; k0 < 1024; k0 += 32) {
    if (k0) __syncthreads();
#pragma unroll
    for (int i = 0; i < 2; ++i) {
      int c = i * 256 + t;
      int row = c >> 2, kc = c & 3;
      int mi = m0 + row;
      if (isq) mi += HISTC + (mi >> 10) * HISTC;
      gload16(lds + c * 16, x16 + (size_t)mi * 1024 + k0 + kc * 8);
      gload16(lds + 8192 + c * 16, Bw + (size_t)(n0 + row) * 1024 + k0 + kc * 8);
    }
    __syncthreads();
    bf16x8 af[4], bfr[4];
#pragma unroll
    for (int m = 0; m < 4; ++m)
      af[m] = *reinterpret_cast<const bf16x8*>(lds + (wr * 64 + m * 16 + lrow) * 64 + lk * 16);
#pragma unroll
    for (int n = 0; n < 4; ++n)
      bfr[n] = *reinterpret_cast<const bf16x8*>(lds + 8192 + (wc * 64 + n * 16 + lrow) * 64 + lk * 16);
#pragma unroll
    for (int m = 0; m < 4; ++m)
#pragma unroll
      for (int n = 0; n < 4; ++n)
        acc[m][n] = __builtin_amdgcn_mfma_f32_16x16x32_bf16(af[m], bfr[n], acc[m][n], 0, 0, 0);
  }

  // ---- RoPE in place via table ----
#pragma unroll
  for (int m = 0; m < 4; ++m)
#pragma unroll
    for (int r = 0; r < 4; ++r) {
      int rl = wr * 64 + m * 16 + lk * 4 + r;
      int pos = isq ? (HISTC + ((m0 + rl) & 1023)) : ((m0 + rl) & 4095);
      float2 cs0 = cstab[pos * 32 + lrow];
      float2 cs1 = cstab[pos * 32 + 16 + lrow];
      float a0 = acc[m][0][r], a2 = acc[m][2][r];
      acc[m][0][r] = a0 * cs0.x - a2 * cs0.y;
      acc[m][2][r] = a2 * cs0.x + a0 * cs0.y;
      float a1 = acc[m][1][r], a3 = acc[m][3][r];
      acc[m][1][r] = a1 * cs1.x - a3 * cs1.y;
      acc[m][3][r] = a3 * cs1.x + a1 * cs1.y;
    }

  const int h = (n0 + wc * 64) >> 6;
  if (!isq) {
    float g4[4], b4[4];
#pragma unroll
    for (int n = 0; n < 4; ++n) { g4[n] = gamma[n * 16 + lrow]; b4[n] = beta[n * 16 + lrow]; }
#pragma unroll
    for (int m = 0; m < 4; ++m)
#pragma unroll
      for (int r = 0; r < 4; ++r) {
        float s1 = acc[m][0][r] + acc[m][1][r] + acc[m][2][r] + acc[m][3][r];
        float s2 = acc[m][0][r] * acc[m][0][r] + acc[m][1][r] * acc[m][1][r] +
                   acc[m][2][r] * acc[m][2][r] + acc[m][3][r] * acc[m][3][r];
#pragma unroll
        for (int mk = 1; mk < 16; mk <<= 1) {
          s1 += __shfl_xor(s1, mk);
          s2 += __shfl_xor(s2, mk);
        }
        float mu = s1 * 0.015625f;
        float var = s2 * 0.015625f - mu * mu;
        float inv = rsqrtf(var + 1e-5f);
#pragma unroll
        for (int n = 0; n < 4; ++n)
          acc[m][n][r] = (acc[m][n][r] - mu) * inv * g4[n] + b4[n];
      }
    const size_t hb = (size_t)((m0 >> 12) * HEADS + h);
#pragma unroll
    for (int m = 0; m < 4; ++m)
#pragma unroll
      for (int r = 0; r < 4; ++r) {
        int pos = (m0 + wr * 64 + m * 16 + lk * 4 + r) & 4095;
#pragma unroll
        for (int n = 0; n < 4; ++n)
          kvn[(hb * SEQ + pos) * DHH + n * 16 + lrow] = (__bf16)acc[m][n][r];
      }
#pragma unroll
    for (int m = 0; m < 4; ++m) {
      int pos0 = (m0 + wr * 64 + m * 16 + lk * 4) & 4095;
      int sp = (pos0 & ~12) | ((pos0 & 4) << 1) | ((pos0 & 8) >> 1);
#pragma unroll
      for (int n = 0; n < 4; ++n) {
        union { __bf16 hh[4]; uint64_t u; } pk;
#pragma unroll
        for (int r = 0; r < 4; ++r) pk.hh[r] = (__bf16)acc[m][n][r];
        *reinterpret_cast<uint64_t*>(kvnT + (hb * DHH + n * 16 + lrow) * SEQ + sp) = pk.u;
      }
    }
  } else {
    const size_t hb = (size_t)((m0 >> 10) * HEADS + h);
#pragma unroll
    for (int m = 0; m < 4; ++m)
#pragma unroll
      for (int r = 0; r < 4; ++r) {
        int qi = (m0 + wr * 64 + m * 16 + lk * 4 + r) & 1023;
#pragma unroll
        for (int n = 0; n < 4; ++n)
          qb[(hb * LATENT + qi) * DHH + n * 16 + lrow] =
              (__bf16)(acc[m][n][r] * 0.18033688011112042f);
      }
  }
}

// ---------------- helpers for flash ----------------
__device__ __forceinline__ float fexp2(float x) {
#if __has_builtin(__builtin_amdgcn_exp2f)
  return __builtin_amdgcn_exp2f(x);
#else
  return exp2f(x);
#endif
}

__device__ __forceinline__ unsigned pk2(float a, float b) {
  union { __bf16 h[2]; unsigned u; } x;
  x.h[0] = (__bf16)a; x.h[1] = (__bf16)b;
  return x.u;
}

// ---------------- flash attention v12: NJ-way j-split, 64-key barrier groups ----
// Same inner math as flash11. NJ=4 -> grid 1024 = 4 blocks/CU (barrier stalls
// of one block hide under other blocks' compute). NJ=2 = flash11 (fallback
// when ws can't hold the 4-way partial buffer).
template<int NJ>
__launch_bounds__(256)
__global__ void k_flash12(const __bf16* __restrict__ qb, const __bf16* __restrict__ kvn,
                          const __bf16* __restrict__ kvnT, float* __restrict__ part) {
  const int bid = blockIdx.x;                  // [0, NJ*256)
  const int xcd = bid & 7;
  const int u = bid >> 3;                      // [0, NJ*32)
  const int jq = u % NJ;
  const int rest = u / NJ;                     // [0,32)
  int itq = rest & 7;
  const int grpb = rest >> 3;                  // [0,4)
  if (grpb >= 2) itq = 7 - itq;                // CU work balance
  const int bh = xcd + 8 * grpb;               // [0,32)
  const int h = bh & 15, b = bh >> 4;
  const int t = threadIdx.x, l = t & 63, w = t >> 6;
  const int q = l & 31, hi = l >> 5;
  const int iw0 = itq * 128;
  const int iwv = iw0 + w * 32;                // wave's first q-row
  const int i = iwv + q;
  const __bf16* qbase = qb + ((size_t)(b * HEADS + h) * LATENT + iwv) * DHH;
  const __bf16* kbase = kvn + (size_t)(b * HEADS + h) * SEQ * DHH;
  const __bf16* vbase = kvnT + (size_t)(b * HEADS + h) * DHH * SEQ;

  __shared__ __align__(16) __bf16 Kl[2][2][32][64];   // [buf][sub][key][d]
  __shared__ __align__(16) __bf16 Vl[2][2][64][32];   // [buf][sub][d][key]

  const int krow = t >> 3, kgc = ((t & 7) ^ (krow & 7)) * 8;   // K: 32 rows x 8 chunks
  const int vrow = t >> 2, vgc = ((t & 3) ^ (vrow & 3)) * 8;   // V: 64 rows x 4 chunks

  bf16x8 qf[4];
#pragma unroll
  for (int c = 0; c < 4; ++c)
    qf[c] = *reinterpret_cast<const bf16x8*>(qbase + (size_t)q * DHH + c * 16 + hi * 8);

  const f32x16 Z = {};
  f32x16 O0 = {}, O1 = {};
  float m_run = -INFINITY, lacc = 0.f;

  const int ng = 2 * itq + 50;                 // 64-key groups total for this q-block
  const int g0 = (ng * jq) / NJ, g1 = (ng * (jq + 1)) / NJ;
  const int sx = q & 3;

  // prologue: stage group g0 -> buf 0 (both subtiles)
  {
    const int ja = g0 * 64;
    gload16((char*)&Kl[0][0][0][0] + t * 16, kbase + (size_t)(ja + krow) * DHH + kgc);
    gload16((char*)&Kl[0][1][0][0] + t * 16, kbase + (size_t)(ja + 32 + krow) * DHH + kgc);
    gload16((char*)&Vl[0][0][0][0] + t * 16, vbase + (size_t)vrow * SEQ + ja + vgc);
    gload16((char*)&Vl[0][1][0][0] + t * 16, vbase + (size_t)vrow * SEQ + ja + 32 + vgc);
  }
  __syncthreads();

  for (int g = g0; g < g1; ++g) {
    const int cur = (g - g0) & 1;
    const int ja = g * 64, jb = ja + 32;
    // ---------------- subtile a: QK ----------------
    const char* Ka = (const char*)&Kl[cur][0][0][0];
    const char* Va = (const char*)&Vl[cur][0][0][0];
    bf16x8 kf0 = *reinterpret_cast<const bf16x8*>(Ka + q * 128 + ((0 + hi) ^ (q & 7)) * 16);
    bf16x8 kf1 = *reinterpret_cast<const bf16x8*>(Ka + q * 128 + ((2 + hi) ^ (q & 7)) * 16);
    bf16x8 kf2 = *reinterpret_cast<const bf16x8*>(Ka + q * 128 + ((4 + hi) ^ (q & 7)) * 16);
    bf16x8 kf3 = *reinterpret_cast<const bf16x8*>(Ka + q * 128 + ((6 + hi) ^ (q & 7)) * 16);
    f32x16 S = __builtin_amdgcn_mfma_f32_32x32x16_bf16(kf0, qf[0], Z, 0, 0, 0);
    S = __builtin_amdgcn_mfma_f32_32x32x16_bf16(kf1, qf[1], S, 0, 0, 0);
    S = __builtin_amdgcn_mfma_f32_32x32x16_bf16(kf2, qf[2], S, 0, 0, 0);
    S = __builtin_amdgcn_mfma_f32_32x32x16_bf16(kf3, qf[3], S, 0, 0, 0);
    // issue next group's stage into the other buffer
    if (g + 1 < g1) {
      const int jn = (g + 1) * 64;
      gload16((char*)&Kl[cur ^ 1][0][0][0] + t * 16, kbase + (size_t)(jn + krow) * DHH + kgc);
      gload16((char*)&Kl[cur ^ 1][1][0][0] + t * 16, kbase + (size_t)(jn + 32 + krow) * DHH + kgc);
      gload16((char*)&Vl[cur ^ 1][0][0][0] + t * 16, vbase + (size_t)vrow * SEQ + jn + vgc);
      gload16((char*)&Vl[cur ^ 1][1][0][0] + t * 16, vbase + (size_t)vrow * SEQ + jn + 32 + vgc);
    }
    // ---------------- subtile a: softmax + PV ----------------
    if (ja + 31 > iwv + HISTC) {
#pragma unroll
      for (int r = 0; r < 16; ++r) {
        int j = ja + (r & 3) + 8 * (r >> 2) + 4 * hi;
        if (j > i + HISTC) S[r] = -1e30f;
      }
    }
    {
      float u1 = fmaxf(fmaxf(S[0], S[1]), S[2]);
      float u2 = fmaxf(fmaxf(S[3], S[4]), S[5]);
      float u3 = fmaxf(fmaxf(S[6], S[7]), S[8]);
      float u4 = fmaxf(fmaxf(S[9], S[10]), S[11]);
      float u5 = fmaxf(fmaxf(S[12], S[13]), S[14]);
      float pm = fmaxf(fmaxf(fmaxf(u1, u2), u3), fmaxf(fmaxf(u4, u5), S[15]));
      if (__any(pm > m_run + 8.0f)) {
        pm = fmaxf(pm, __shfl_xor(pm, 32));
        float mn = fmaxf(m_run, pm);
        float sc = fexp2(m_run - mn);
        m_run = mn;
        lacc *= sc;
#pragma unroll
        for (int r = 0; r < 16; ++r) { O0[r] *= sc; O1[r] *= sc; }
      }
      float p[16];
#pragma unroll
      for (int r = 0; r < 16; ++r) p[r] = fexp2(S[r] - m_run);
      float s8[8];
#pragma unroll
      for (int r = 0; r < 8; ++r) s8[r] = p[r] + p[r + 8];
      lacc += ((s8[0] + s8[4]) + (s8[1] + s8[5])) + ((s8[2] + s8[6]) + (s8[3] + s8[7]));
      union { unsigned u[4]; bf16x8 v; } pf0, pf1;
      pf0.u[0] = pk2(p[0], p[1]);   pf0.u[1] = pk2(p[2], p[3]);
      pf0.u[2] = pk2(p[4], p[5]);   pf0.u[3] = pk2(p[6], p[7]);
      pf1.u[0] = pk2(p[8], p[9]);   pf1.u[1] = pk2(p[10], p[11]);
      pf1.u[2] = pk2(p[12], p[13]); pf1.u[3] = pk2(p[14], p[15]);
      bf16x8 va00 = *reinterpret_cast<const bf16x8*>(Va + q * 64 + (hi ^ sx) * 16);
      bf16x8 va01 = *reinterpret_cast<const bf16x8*>(Va + q * 64 + ((2 + hi) ^ sx) * 16);
      bf16x8 va10 = *reinterpret_cast<const bf16x8*>(Va + (32 + q) * 64 + (hi ^ sx) * 16);
      bf16x8 va11 = *reinterpret_cast<const bf16x8*>(Va + (32 + q) * 64 + ((2 + hi) ^ sx) * 16);
      O0 = __builtin_amdgcn_mfma_f32_32x32x16_bf16(va00, pf0.v, O0, 0, 0, 0);
      O0 = __builtin_amdgcn_mfma_f32_32x32x16_bf16(va01, pf1.v, O0, 0, 0, 0);
      O1 = __builtin_amdgcn_mfma_f32_32x32x16_bf16(va10, pf0.v, O1, 0, 0, 0);
      O1 = __builtin_amdgcn_mfma_f32_32x32x16_bf16(va11, pf1.v, O1, 0, 0, 0);
    }
    // ---------------- subtile b ----------------
    const char* Kb = (const char*)&Kl[cur][1][0][0];
    const char* Vb = (const char*)&Vl[cur][1][0][0];
    bf16x8 kg0 = *reinterpret_cast<const bf16x8*>(Kb + q * 128 + ((0 + hi) ^ (q & 7)) * 16);
    bf16x8 kg1 = *reinterpret_cast<const bf16x8*>(Kb + q * 128 + ((2 + hi) ^ (q & 7)) * 16);
    bf16x8 kg2 = *reinterpret_cast<const bf16x8*>(Kb + q * 128 + ((4 + hi) ^ (q & 7)) * 16);
    bf16x8 kg3 = *reinterpret_cast<const bf16x8*>(Kb + q * 128 + ((6 + hi) ^ (q & 7)) * 16);
    f32x16 T = __builtin_amdgcn_mfma_f32_32x32x16_bf16(kg0, qf[0], Z, 0, 0, 0);
    T = __builtin_amdgcn_mfma_f32_32x32x16_bf16(kg1, qf[1], T, 0, 0, 0);
    T = __builtin_amdgcn_mfma_f32_32x32x16_bf16(kg2, qf[2], T, 0, 0, 0);
    T = __builtin_amdgcn_mfma_f32_32x32x16_bf16(kg3, qf[3], T, 0, 0, 0);
    if (jb + 31 > iwv + HISTC) {
#pragma unroll
      for (int r = 0; r < 16; ++r) {
        int j = jb + (r & 3) + 8 * (r >> 2) + 4 * hi;
        if (j > i + HISTC) T[r] = -1e30f;
      }
    }
    {
      float u1 = fmaxf(fmaxf(T[0], T[1]), T[2]);
      float u2 = fmaxf(fmaxf(T[3], T[4]), T[5]);
      float u3 = fmaxf(fmaxf(T[6], T[7]), T[8]);
      float u4 = fmaxf(fmaxf(T[9], T[10]), T[11]);
      float u5 = fmaxf(fmaxf(T[12], T[13]), T[14]);
      float pm = fmaxf(fmaxf(fmaxf(u1, u2), u3), fmaxf(fmaxf(u4, u5), T[15]));
      if (__any(pm > m_run + 8.0f)) {
        pm = fmaxf(pm, __shfl_xor(pm, 32));
        float mn = fmaxf(m_run, pm);
        float sc = fexp2(m_run - mn);
        m_run = mn;
        lacc *= sc;
#pragma unroll
        for (int r = 0; r < 16; ++r) { O0[r] *= sc; O1[r] *= sc; }
      }
      float p[16];
#pragma unroll
      for (int r = 0; r < 16; ++r) p[r] = fexp2(T[r] - m_run);
      float s8[8];
#pragma unroll
      for (int r = 0; r < 8; ++r) s8[r] = p[r] + p[r + 8];
      lacc += ((s8[0] + s8[4]) + (s8[1] + s8[5])) + ((s8[2] + s8[6]) + (s8[3] + s8[7]));
      union { unsigned u[4]; bf16x8 v; } pf0, pf1;
      pf0.u[0] = pk2(p[0], p[1]);   pf0.u[1] = pk2(p[2], p[3]);
      pf0.u[2] = pk2(p[4], p[5]);   pf0.u[3] = pk2(p[6], p[7]);
      pf1.u[0] = pk2(p[8], p[9]);   pf1.u[1] = pk2(p[10], p[11]);
      pf1.u[2] = pk2(p[12], p[13]); pf1.u[3] = pk2(p[14], p[15]);
      bf16x8 vb00 = *reinterpret_cast<const bf16x8*>(Vb + q * 64 + (hi ^ sx) * 16);
      bf16x8 vb01 = *reinterpret_cast<const bf16x8*>(Vb + q * 64 + ((2 + hi) ^ sx) * 16);
      bf16x8 vb10 = *reinterpret_cast<const bf16x8*>(Vb + (32 + q) * 64 + (hi ^ sx) * 16);
      bf16x8 vb11 = *reinterpret_cast<const bf16x8*>(Vb + (32 + q) * 64 + ((2 + hi) ^ sx) * 16);
      O0 = __builtin_amdgcn_mfma_f32_32x32x16_bf16(vb00, pf0.v, O0, 0, 0, 0);
      O0 = __builtin_amdgcn_mfma_f32_32x32x16_bf16(vb01, pf1.v, O0, 0, 0, 0);
      O1 = __builtin_amdgcn_mfma_f32_32x32x16_bf16(vb10, pf0.v, O1, 0, 0, 0);
      O1 = __builtin_amdgcn_mfma_f32_32x32x16_bf16(vb11, pf1.v, O1, 0, 0, 0);
    }
    __syncthreads();   // drain stage(g+1), sync readers before buf reuse
  }
  float l_run = lacc + __shfl_xor(lacc, 32);

  // -------- wave-final partial dump (reg-major, coalesced) --------
  const int pidx = (bh * 8 + itq) * NJ + jq;
  float* pw = part + (size_t)(pidx * 4 + w) * 34 * 64;
#pragma unroll
  for (int r = 0; r < 16; ++r) pw[r * 64 + l] = O0[r];
#pragma unroll
  for (int r = 0; r < 16; ++r) pw[(16 + r) * 64 + l] = O1[r];
  pw[32 * 64 + l] = m_run;
  pw[33 * 64 + l] = l_run;
}

// ---------------- merge the NJ j-split partials -> aout (bf16) ----------------
template<int NJ>
__global__ void k_fmerge12(const float* __restrict__ part, __bf16* __restrict__ aout) {
  const int u = blockIdx.x;                    // [0,256) = bh*8 + itq
  const int bh = u >> 3, itq = u & 7;
  const int b = bh >> 4, h = bh & 15;
  const int t = threadIdx.x;
  const int w = t >> 6, sub = t & 63, q = sub & 31, hi = sub >> 5;
  const float* pp[NJ];
#pragma unroll
  for (int j = 0; j < NJ; ++j)
    pp[j] = part + (size_t)((u * NJ + j) * 4 + w) * 34 * 64;
  float mm = -INFINITY;
#pragma unroll
  for (int j = 0; j < NJ; ++j) mm = fmaxf(mm, pp[j][32 * 64 + sub]);
  float sc[NJ];
  float ll = 0.f;
#pragma unroll
  for (int j = 0; j < NJ; ++j) {
    sc[j] = fexp2(pp[j][32 * 64 + sub] - mm);
    ll += pp[j][33 * 64 + sub] * sc[j];
  }
  float inv = 1.f / ll;
  const int row = itq * 128 + w * 32 + q;
  __bf16* orow = aout + ((size_t)(b * LATENT) + row) * DIMC + h * DHH;
#pragma unroll
  for (int g = 0; g < 4; ++g) {
    union { __bf16 hh[4]; uint2 u2; } pk;
#pragma unroll
    for (int e = 0; e < 4; ++e) {
      float o = 0.f;
#pragma unroll
      for (int j = 0; j < NJ; ++j) o += pp[j][(4 * g + e) * 64 + sub] * sc[j];
      pk.hh[e] = (__bf16)(o * inv);
    }
    *reinterpret_cast<uint2*>(orow + 8 * g + 4 * hi) = pk.u2;
#pragma unroll
    for (int e = 0; e < 4; ++e) {
      float o = 0.f;
#pragma unroll
      for (int j = 0; j < NJ; ++j) o += pp[j][(16 + 4 * g + e) * 64 + sub] * sc[j];
      pk.hh[e] = (__bf16)(o * inv);
    }
    *reinterpret_cast<uint2*>(orow + 32 + 8 * g + 4 * hi) = pk.u2;
  }
}

// ---------------- host launcher ----------------
extern "C" void kernel_launch(void* const* d_in, const int* in_sizes, int n_in,
                              void* d_out, int out_size, void* d_ws, size_t ws_size,
                              hipStream_t stream) {
  const float* x = (const float*)d_in[0];
  const float* Wq = (const float*)d_in[1];
  const float* Wkv = (const float*)d_in[2];
  const float* Wo = (const float*)d_in[3];
  const float* bo = (const float*)d_in[4];
  const float* gamma = (const float*)d_in[5];
  const float* beta = (const float*)d_in[6];

  char* ws = (char*)d_ws;
  size_t o = 0;
  __bf16* x16 = (__bf16*)(ws + o);  o += (size_t)BATCH * SEQ * DIMC * 2;
  __bf16* wq16 = (__bf16*)(ws + o); o += (size_t)DIMC * DIMC * 2;
  __bf16* wkv16 = (__bf16*)(ws + o); o += (size_t)DIMC * DIMC * 2;
  __bf16* wo16 = (__bf16*)(ws + o); o += (size_t)DIMC * DIMC * 2;
  float2* cstab = (float2*)(ws + o); o += (size_t)SEQ * 32 * 8;
  __bf16* kvn = (__bf16*)(ws + o);  o += (size_t)BATCH * HEADS * SEQ * DHH * 2;
  __bf16* kvnT = (__bf16*)(ws + o); o += (size_t)BATCH * HEADS * SEQ * DHH * 2;
  __bf16* qb = (__bf16*)(ws + o);   o += (size_t)BATCH * HEADS * LATENT * DHH * 2;
  __bf16* aout = (__bf16*)(ws + o); o += (size_t)BATCH * LATENT * DIMC * 2;
  float* part = (float*)(ws + o);
  const size_t part4 = (size_t)1024 * 4 * 34 * 64 * 4;   // NJ=4 partials (35.7 MB)
  const bool use4 = (ws_size - o) >= part4;

  k_prep<<<4096, 256, 0, stream>>>(x, Wq, Wkv, Wo, x16, wq16, wkv16, wo16, cstab);
  k_gemmqkv<<<640, 256, 0, stream>>>(x16, wkv16, wq16, kvn, kvnT, qb, gamma, beta, cstab);
  if (use4) {
    k_flash12<4><<<1024, 256, 0, stream>>>(qb, kvn, kvnT, part);
    k_fmerge12<4><<<256, 256, 0, stream>>>(part, aout);
  } else {
    k_flash12<2><<<512, 256, 0, stream>>>(qb, kvn, kvnT, part);
    k_fmerge12<2><<<256, 256, 0, stream>>>(part, aout);
  }
  k_gemm<1><<<128, 256, 0, stream>>>(aout, wo16, (float*)d_out, bo, 2048, 1024, 1024);
}

// Round 16
// 141.204 us; speedup vs baseline: 1.0826x; 1.0826x over previous
//
#include <hip/hip_runtime.h>
#include <hip/hip_bf16.h>
#include <cstdint>

#define DIMC 1024
#define HEADS 16
#define DHH 64
#define SEQ 4096
#define LATENT 1024
#define HISTC 3072
#define BATCH 2

typedef __attribute__((ext_vector_type(8))) __bf16 bf16x8;
typedef __attribute__((ext_vector_type(4))) float f32x4;
typedef __attribute__((ext_vector_type(16))) float f32x16;

// ---------------- fused prep: x->bf16, 3 weights->bf16, RoPE cos/sin table ----
__global__ void k_prep(const float* __restrict__ x, const float* __restrict__ Wq,
                       const float* __restrict__ Wkv, const float* __restrict__ Wo,
                       __bf16* __restrict__ x16, __bf16* __restrict__ wq16,
                       __bf16* __restrict__ wkv16, __bf16* __restrict__ wo16,
                       float2* __restrict__ cs) {
  int bidx = blockIdx.x;
  if (bidx < 2048) {
    int base = bidx * 256 + threadIdx.x;
#pragma unroll
    for (int k = 0; k < 4; ++k) {
      int i = base + k * 524288;
      float4 v = reinterpret_cast<const float4*>(x)[i];
      union { __bf16 h[4]; uint64_t u; } p;
      p.h[0] = (__bf16)v.x; p.h[1] = (__bf16)v.y;
      p.h[2] = (__bf16)v.z; p.h[3] = (__bf16)v.w;
      reinterpret_cast<uint64_t*>(x16)[i] = p.u;
    }
  } else if (bidx < 3584) {
    int id = bidx - 2048;
    const float* src; __bf16* dst;
    if (id < 512) { src = Wq; dst = wq16; }
    else if (id < 1024) { src = Wkv; dst = wkv16; id -= 512; }
    else { src = Wo; dst = wo16; id -= 1024; }
#pragma unroll
    for (int k = 0; k < 2; ++k) {
      int idx = id * 512 + k * 256 + threadIdx.x;
      float4 v = reinterpret_cast<const float4*>(src)[idx];
      union { __bf16 h[4]; uint64_t u; } p;
      p.h[0] = (__bf16)v.x; p.h[1] = (__bf16)v.y;
      p.h[2] = (__bf16)v.z; p.h[3] = (__bf16)v.w;
      reinterpret_cast<uint64_t*>(dst)[idx] = p.u;
    }
  } else {
    int idx = (bidx - 3584) * 256 + threadIdx.x;   // 4096*32 entries
    int pos = idx >> 5, f = idx & 31;
    float invf = exp2f(-(float)f * 0.41524101186f);  // log2(10000)/32
    float s, c;
    sincosf((float)pos * invf, &s, &c);
    cs[idx] = make_float2(c, s);
  }
}

// ---------------- async global->LDS 16B ----------------
__device__ __forceinline__ void gload16(void* lds, const void* g) {
  __builtin_amdgcn_global_load_lds(
      (const __attribute__((address_space(1))) unsigned int*)g,
      (__attribute__((address_space(3))) unsigned int*)lds, 16, 0, 0);
}

// ---------------- plain GEMM (o-proj): C = A @ Bw^T + bias ----
// BK=64 (half the barriers of BK=32); chunk-XOR swizzled LDS (pre-swizzled
// global source + linear gload_lds dest, rule #21).
template<int BIAS>
__launch_bounds__(256)
__global__ void k_gemm(const __bf16* __restrict__ A, const __bf16* __restrict__ Bw,
                       float* __restrict__ C, const float* __restrict__ bias,
                       int M, int N, int K) {
  __shared__ __align__(16) char lds[32768];
  const int t = threadIdx.x;
  const int l = t & 63, w = t >> 6;
  const int wr = w >> 1, wc = w & 1;
  const int mblocks = M >> 7;
  const int m0 = (blockIdx.x % mblocks) * 128, n0 = (blockIdx.x / mblocks) * 128;
  const int lrow = l & 15, lk = l >> 4;
  f32x4 acc[4][4] = {};

  for (int k0 = 0; k0 < K; k0 += 64) {
    if (k0) __syncthreads();
#pragma unroll
    for (int i = 0; i < 4; ++i) {
      int c = i * 256 + t;                 // [0,1024): chunk id
      int row = c >> 3;
      int kgc = ((c & 7) ^ (row & 7)) * 8; // pre-swizzled source chunk
      gload16(lds + c * 16, A + (size_t)(m0 + row) * K + k0 + kgc);
      gload16(lds + 16384 + c * 16, Bw + (size_t)(n0 + row) * K + k0 + kgc);
    }
    __syncthreads();
#pragma unroll
    for (int ks = 0; ks < 2; ++ks) {
      bf16x8 af[4], bfr[4];
#pragma unroll
      for (int m = 0; m < 4; ++m) {
        int row = wr * 64 + m * 16 + lrow;
        af[m] = *reinterpret_cast<const bf16x8*>(
            lds + row * 128 + ((ks * 4 + lk) ^ (row & 7)) * 16);
      }
#pragma unroll
      for (int n = 0; n < 4; ++n) {
        int row = wc * 64 + n * 16 + lrow;
        bfr[n] = *reinterpret_cast<const bf16x8*>(
            lds + 16384 + row * 128 + ((ks * 4 + lk) ^ (row & 7)) * 16);
      }
#pragma unroll
      for (int m = 0; m < 4; ++m)
#pragma unroll
        for (int n = 0; n < 4; ++n)
          acc[m][n] = __builtin_amdgcn_mfma_f32_16x16x32_bf16(af[m], bfr[n], acc[m][n], 0, 0, 0);
    }
  }

#pragma unroll
  for (int m = 0; m < 4; ++m)
#pragma unroll
    for (int n = 0; n < 4; ++n)
#pragma unroll
      for (int r = 0; r < 4; ++r) {
        int row = m0 + wr * 64 + m * 16 + (l >> 4) * 4 + r;
        int col = n0 + wc * 64 + n * 16 + (l & 15);
        float v = acc[m][n][r];
        if (BIAS) v += bias[col];
        C[(size_t)row * N + col] = v;
      }
}

// ---------------- fused QKV GEMM: kv-proj(+RoPE+LN) and q-proj(+RoPE+scale) ----
// BK=64 + chunk-XOR swizzle (as k_gemm). Epilogue unchanged.
__launch_bounds__(256)
__global__ void k_gemmqkv(const __bf16* __restrict__ x16,
                          const __bf16* __restrict__ wkv16,
                          const __bf16* __restrict__ wq16,
                          __bf16* __restrict__ kvn, __bf16* __restrict__ kvnT,
                          __bf16* __restrict__ qb,
                          const float* __restrict__ gamma,
                          const float* __restrict__ beta,
                          const float2* __restrict__ cstab) {
  __shared__ __align__(16) char lds[32768];
  const int t = threadIdx.x, l = t & 63, w = t >> 6;
  const int wr = w >> 1, wc = w & 1;
  const int by = blockIdx.x % 80;
  const bool isq = by >= 64;
  const int m0 = (isq ? (by - 64) : by) * 128;
  const int n0 = (blockIdx.x / 80) * 128;
  const __bf16* Bw = isq ? wq16 : wkv16;
  const int lrow = l & 15, lk = l >> 4;
  f32x4 acc[4][4] = {};

  for (int k0 = 0; k0 < 1024; k0 += 64) {
    if (k0) __syncthreads();
#pragma unroll
    for (int i = 0; i < 4; ++i) {
      int c = i * 256 + t;
      int row = c >> 3;
      int kgc = ((c & 7) ^ (row & 7)) * 8;
      int mi = m0 + row;
      if (isq) mi += HISTC + (mi >> 10) * HISTC;
      gload16(lds + c * 16, x16 + (size_t)mi * 1024 + k0 + kgc);
      gload16(lds + 16384 + c * 16, Bw + (size_t)(n0 + row) * 1024 + k0 + kgc);
    }
    __syncthreads();
#pragma unroll
    for (int ks = 0; ks < 2; ++ks) {
      bf16x8 af[4], bfr[4];
#pragma unroll
      for (int m = 0; m < 4; ++m) {
        int row = wr * 64 + m * 16 + lrow;
        af[m] = *reinterpret_cast<const bf16x8*>(
            lds + row * 128 + ((ks * 4 + lk) ^ (row & 7)) * 16);
      }
#pragma unroll
      for (int n = 0; n < 4; ++n) {
        int row = wc * 64 + n * 16 + lrow;
        bfr[n] = *reinterpret_cast<const bf16x8*>(
            lds + 16384 + row * 128 + ((ks * 4 + lk) ^ (row & 7)) * 16);
      }
#pragma unroll
      for (int m = 0; m < 4; ++m)
#pragma unroll
        for (int n = 0; n < 4; ++n)
          acc[m][n] = __builtin_amdgcn_mfma_f32_16x16x32_bf16(af[m], bfr[n], acc[m][n], 0, 0, 0);
    }
  }

  // ---- RoPE in place via table ----
#pragma unroll
  for (int m = 0; m < 4; ++m)
#pragma unroll
    for (int r = 0; r < 4; ++r) {
      int rl = wr * 64 + m * 16 + lk * 4 + r;
      int pos = isq ? (HISTC + ((m0 + rl) & 1023)) : ((m0 + rl) & 4095);
      float2 cs0 = cstab[pos * 32 + lrow];
      float2 cs1 = cstab[pos * 32 + 16 + lrow];
      float a0 = acc[m][0][r], a2 = acc[m][2][r];
      acc[m][0][r] = a0 * cs0.x - a2 * cs0.y;
      acc[m][2][r] = a2 * cs0.x + a0 * cs0.y;
      float a1 = acc[m][1][r], a3 = acc[m][3][r];
      acc[m][1][r] = a1 * cs1.x - a3 * cs1.y;
      acc[m][3][r] = a3 * cs1.x + a1 * cs1.y;
    }

  const int h = (n0 + wc * 64) >> 6;
  if (!isq) {
    float g4[4], b4[4];
#pragma unroll
    for (int n = 0; n < 4; ++n) { g4[n] = gamma[n * 16 + lrow]; b4[n] = beta[n * 16 + lrow]; }
#pragma unroll
    for (int m = 0; m < 4; ++m)
#pragma unroll
      for (int r = 0; r < 4; ++r) {
        float s1 = acc[m][0][r] + acc[m][1][r] + acc[m][2][r] + acc[m][3][r];
        float s2 = acc[m][0][r] * acc[m][0][r] + acc[m][1][r] * acc[m][1][r] +
                   acc[m][2][r] * acc[m][2][r] + acc[m][3][r] * acc[m][3][r];
#pragma unroll
        for (int mk = 1; mk < 16; mk <<= 1) {
          s1 += __shfl_xor(s1, mk);
          s2 += __shfl_xor(s2, mk);
        }
        float mu = s1 * 0.015625f;
        float var = s2 * 0.015625f - mu * mu;
        float inv = rsqrtf(var + 1e-5f);
#pragma unroll
        for (int n = 0; n < 4; ++n)
          acc[m][n][r] = (acc[m][n][r] - mu) * inv * g4[n] + b4[n];
      }
    const size_t hb = (size_t)((m0 >> 12) * HEADS + h);
#pragma unroll
    for (int m = 0; m < 4; ++m)
#pragma unroll
      for (int r = 0; r < 4; ++r) {
        int pos = (m0 + wr * 64 + m * 16 + lk * 4 + r) & 4095;
#pragma unroll
        for (int n = 0; n < 4; ++n)
          kvn[(hb * SEQ + pos) * DHH + n * 16 + lrow] = (__bf16)acc[m][n][r];
      }
#pragma unroll
    for (int m = 0; m < 4; ++m) {
      int pos0 = (m0 + wr * 64 + m * 16 + lk * 4) & 4095;
      int sp = (pos0 & ~12) | ((pos0 & 4) << 1) | ((pos0 & 8) >> 1);
#pragma unroll
      for (int n = 0; n < 4; ++n) {
        union { __bf16 hh[4]; uint64_t u; } pk;
#pragma unroll
        for (int r = 0; r < 4; ++r) pk.hh[r] = (__bf16)acc[m][n][r];
        *reinterpret_cast<uint64_t*>(kvnT + (hb * DHH + n * 16 + lrow) * SEQ + sp) = pk.u;
      }
    }
  } else {
    const size_t hb = (size_t)((m0 >> 10) * HEADS + h);
#pragma unroll
    for (int m = 0; m < 4; ++m)
#pragma unroll
      for (int r = 0; r < 4; ++r) {
        int qi = (m0 + wr * 64 + m * 16 + lk * 4 + r) & 1023;
#pragma unroll
        for (int n = 0; n < 4; ++n)
          qb[(hb * LATENT + qi) * DHH + n * 16 + lrow] =
              (__bf16)(acc[m][n][r] * 0.18033688011112042f);
      }
  }
}

// ---------------- helpers for flash ----------------
__device__ __forceinline__ float fexp2(float x) {
#if __has_builtin(__builtin_amdgcn_exp2f)
  return __builtin_amdgcn_exp2f(x);
#else
  return exp2f(x);
#endif
}

__device__ __forceinline__ unsigned pk2(float a, float b) {
  union { __bf16 h[2]; unsigned u; } x;
  x.h[0] = (__bf16)a; x.h[1] = (__bf16)b;
  return x.u;
}

// ---------------- flash attention v12 (NJ=2, verified 62.9us) ----------------
template<int NJ>
__launch_bounds__(256)
__global__ void k_flash12(const __bf16* __restrict__ qb, const __bf16* __restrict__ kvn,
                          const __bf16* __restrict__ kvnT, float* __restrict__ part) {
  const int bid = blockIdx.x;                  // [0, NJ*256)
  const int xcd = bid & 7;
  const int u = bid >> 3;                      // [0, NJ*32)
  const int jq = u % NJ;
  const int rest = u / NJ;                     // [0,32)
  int itq = rest & 7;
  const int grpb = rest >> 3;                  // [0,4)
  if (grpb >= 2) itq = 7 - itq;                // CU work balance
  const int bh = xcd + 8 * grpb;               // [0,32)
  const int h = bh & 15, b = bh >> 4;
  const int t = threadIdx.x, l = t & 63, w = t >> 6;
  const int q = l & 31, hi = l >> 5;
  const int iw0 = itq * 128;
  const int iwv = iw0 + w * 32;                // wave's first q-row
  const int i = iwv + q;
  const __bf16* qbase = qb + ((size_t)(b * HEADS + h) * LATENT + iwv) * DHH;
  const __bf16* kbase = kvn + (size_t)(b * HEADS + h) * SEQ * DHH;
  const __bf16* vbase = kvnT + (size_t)(b * HEADS + h) * DHH * SEQ;

  __shared__ __align__(16) __bf16 Kl[2][2][32][64];   // [buf][sub][key][d]
  __shared__ __align__(16) __bf16 Vl[2][2][64][32];   // [buf][sub][d][key]

  const int krow = t >> 3, kgc = ((t & 7) ^ (krow & 7)) * 8;   // K: 32 rows x 8 chunks
  const int vrow = t >> 2, vgc = ((t & 3) ^ (vrow & 3)) * 8;   // V: 64 rows x 4 chunks

  bf16x8 qf[4];
#pragma unroll
  for (int c = 0; c < 4; ++c)
    qf[c] = *reinterpret_cast<const bf16x8*>(qbase + (size_t)q * DHH + c * 16 + hi * 8);

  const f32x16 Z = {};
  f32x16 O0 = {}, O1 = {};
  float m_run = -INFINITY, lacc = 0.f;

  const int ng = 2 * itq + 50;                 // 64-key groups total for this q-block
  const int g0 = (ng * jq) / NJ, g1 = (ng * (jq + 1)) / NJ;
  const int sx = q & 3;

  // prologue: stage group g0 -> buf 0 (both subtiles)
  {
    const int ja = g0 * 64;
    gload16((char*)&Kl[0][0][0][0] + t * 16, kbase + (size_t)(ja + krow) * DHH + kgc);
    gload16((char*)&Kl[0][1][0][0] + t * 16, kbase + (size_t)(ja + 32 + krow) * DHH + kgc);
    gload16((char*)&Vl[0][0][0][0] + t * 16, vbase + (size_t)vrow * SEQ + ja + vgc);
    gload16((char*)&Vl[0][1][0][0] + t * 16, vbase + (size_t)vrow * SEQ + ja + 32 + vgc);
  }
  __syncthreads();

  for (int g = g0; g < g1; ++g) {
    const int cur = (g - g0) & 1;
    const int ja = g * 64, jb = ja + 32;
    // ---------------- subtile a: QK ----------------
    const char* Ka = (const char*)&Kl[cur][0][0][0];
    const char* Va = (const char*)&Vl[cur][0][0][0];
    bf16x8 kf0 = *reinterpret_cast<const bf16x8*>(Ka + q * 128 + ((0 + hi) ^ (q & 7)) * 16);
    bf16x8 kf1 = *reinterpret_cast<const bf16x8*>(Ka + q * 128 + ((2 + hi) ^ (q & 7)) * 16);
    bf16x8 kf2 = *reinterpret_cast<const bf16x8*>(Ka + q * 128 + ((4 + hi) ^ (q & 7)) * 16);
    bf16x8 kf3 = *reinterpret_cast<const bf16x8*>(Ka + q * 128 + ((6 + hi) ^ (q & 7)) * 16);
    f32x16 S = __builtin_amdgcn_mfma_f32_32x32x16_bf16(kf0, qf[0], Z, 0, 0, 0);
    S = __builtin_amdgcn_mfma_f32_32x32x16_bf16(kf1, qf[1], S, 0, 0, 0);
    S = __builtin_amdgcn_mfma_f32_32x32x16_bf16(kf2, qf[2], S, 0, 0, 0);
    S = __builtin_amdgcn_mfma_f32_32x32x16_bf16(kf3, qf[3], S, 0, 0, 0);
    // issue next group's stage into the other buffer
    if (g + 1 < g1) {
      const int jn = (g + 1) * 64;
      gload16((char*)&Kl[cur ^ 1][0][0][0] + t * 16, kbase + (size_t)(jn + krow) * DHH + kgc);
      gload16((char*)&Kl[cur ^ 1][1][0][0] + t * 16, kbase + (size_t)(jn + 32 + krow) * DHH + kgc);
      gload16((char*)&Vl[cur ^ 1][0][0][0] + t * 16, vbase + (size_t)vrow * SEQ + jn + vgc);
      gload16((char*)&Vl[cur ^ 1][1][0][0] + t * 16, vbase + (size_t)vrow * SEQ + jn + 32 + vgc);
    }
    // ---------------- subtile a: softmax + PV ----------------
    if (ja + 31 > iwv + HISTC) {
#pragma unroll
      for (int r = 0; r < 16; ++r) {
        int j = ja + (r & 3) + 8 * (r >> 2) + 4 * hi;
        if (j > i + HISTC) S[r] = -1e30f;
      }
    }
    {
      float u1 = fmaxf(fmaxf(S[0], S[1]), S[2]);
      float u2 = fmaxf(fmaxf(S[3], S[4]), S[5]);
      float u3 = fmaxf(fmaxf(S[6], S[7]), S[8]);
      float u4 = fmaxf(fmaxf(S[9], S[10]), S[11]);
      float u5 = fmaxf(fmaxf(S[12], S[13]), S[14]);
      float pm = fmaxf(fmaxf(fmaxf(u1, u2), u3), fmaxf(fmaxf(u4, u5), S[15]));
      if (__any(pm > m_run + 8.0f)) {
        pm = fmaxf(pm, __shfl_xor(pm, 32));
        float mn = fmaxf(m_run, pm);
        float sc = fexp2(m_run - mn);
        m_run = mn;
        lacc *= sc;
#pragma unroll
        for (int r = 0; r < 16; ++r) { O0[r] *= sc; O1[r] *= sc; }
      }
      float p[16];
#pragma unroll
      for (int r = 0; r < 16; ++r) p[r] = fexp2(S[r] - m_run);
      float s8[8];
#pragma unroll
      for (int r = 0; r < 8; ++r) s8[r] = p[r] + p[r + 8];
      lacc += ((s8[0] + s8[4]) + (s8[1] + s8[5])) + ((s8[2] + s8[6]) + (s8[3] + s8[7]));
      union { unsigned u[4]; bf16x8 v; } pf0, pf1;
      pf0.u[0] = pk2(p[0], p[1]);   pf0.u[1] = pk2(p[2], p[3]);
      pf0.u[2] = pk2(p[4], p[5]);   pf0.u[3] = pk2(p[6], p[7]);
      pf1.u[0] = pk2(p[8], p[9]);   pf1.u[1] = pk2(p[10], p[11]);
      pf1.u[2] = pk2(p[12], p[13]); pf1.u[3] = pk2(p[14], p[15]);
      bf16x8 va00 = *reinterpret_cast<const bf16x8*>(Va + q * 64 + (hi ^ sx) * 16);
      bf16x8 va01 = *reinterpret_cast<const bf16x8*>(Va + q * 64 + ((2 + hi) ^ sx) * 16);
      bf16x8 va10 = *reinterpret_cast<const bf16x8*>(Va + (32 + q) * 64 + (hi ^ sx) * 16);
      bf16x8 va11 = *reinterpret_cast<const bf16x8*>(Va + (32 + q) * 64 + ((2 + hi) ^ sx) * 16);
      O0 = __builtin_amdgcn_mfma_f32_32x32x16_bf16(va00, pf0.v, O0, 0, 0, 0);
      O0 = __builtin_amdgcn_mfma_f32_32x32x16_bf16(va01, pf1.v, O0, 0, 0, 0);
      O1 = __builtin_amdgcn_mfma_f32_32x32x16_bf16(va10, pf0.v, O1, 0, 0, 0);
      O1 = __builtin_amdgcn_mfma_f32_32x32x16_bf16(va11, pf1.v, O1, 0, 0, 0);
    }
    // ---------------- subtile b ----------------
    const char* Kb = (const char*)&Kl[cur][1][0][0];
    const char* Vb = (const char*)&Vl[cur][1][0][0];
    bf16x8 kg0 = *reinterpret_cast<const bf16x8*>(Kb + q * 128 + ((0 + hi) ^ (q & 7)) * 16);
    bf16x8 kg1 = *reinterpret_cast<const bf16x8*>(Kb + q * 128 + ((2 + hi) ^ (q & 7)) * 16);
    bf16x8 kg2 = *reinterpret_cast<const bf16x8*>(Kb + q * 128 + ((4 + hi) ^ (q & 7)) * 16);
    bf16x8 kg3 = *reinterpret_cast<const bf16x8*>(Kb + q * 128 + ((6 + hi) ^ (q & 7)) * 16);
    f32x16 T = __builtin_amdgcn_mfma_f32_32x32x16_bf16(kg0, qf[0], Z, 0, 0, 0);
    T = __builtin_amdgcn_mfma_f32_32x32x16_bf16(kg1, qf[1], T, 0, 0, 0);
    T = __builtin_amdgcn_mfma_f32_32x32x16_bf16(kg2, qf[2], T, 0, 0, 0);
    T = __builtin_amdgcn_mfma_f32_32x32x16_bf16(kg3, qf[3], T, 0, 0, 0);
    if (jb + 31 > iwv + HISTC) {
#pragma unroll
      for (int r = 0; r < 16; ++r) {
        int j = jb + (r & 3) + 8 * (r >> 2) + 4 * hi;
        if (j > i + HISTC) T[r] = -1e30f;
      }
    }
    {
      float u1 = fmaxf(fmaxf(T[0], T[1]), T[2]);
      float u2 = fmaxf(fmaxf(T[3], T[4]), T[5]);
      float u3 = fmaxf(fmaxf(T[6], T[7]), T[8]);
      float u4 = fmaxf(fmaxf(T[9], T[10]), T[11]);
      float u5 = fmaxf(fmaxf(T[12], T[13]), T[14]);
      float pm = fmaxf(fmaxf(fmaxf(u1, u2), u3), fmaxf(fmaxf(u4, u5), T[15]));
      if (__any(pm > m_run + 8.0f)) {
        pm = fmaxf(pm, __shfl_xor(pm, 32));
        float mn = fmaxf(m_run, pm);
        float sc = fexp2(m_run - mn);
        m_run = mn;
        lacc *= sc;
#pragma unroll
        for (int r = 0; r < 16; ++r) { O0[r] *= sc; O1[r] *= sc; }
      }
      float p[16];
#pragma unroll
      for (int r = 0; r < 16; ++r) p[r] = fexp2(T[r] - m_run);
      float s8[8];
#pragma unroll
      for (int r = 0; r < 8; ++r) s8[r] = p[r] + p[r + 8];
      lacc += ((s8[0] + s8[4]) + (s8[1] + s8[5])) + ((s8[2] + s8[6]) + (s8[3] + s8[7]));
      union { unsigned u[4]; bf16x8 v; } pf0, pf1;
      pf0.u[0] = pk2(p[0], p[1]);   pf0.u[1] = pk2(p[2], p[3]);
      pf0.u[2] = pk2(p[4], p[5]);   pf0.u[3] = pk2(p[6], p[7]);
      pf1.u[0] = pk2(p[8], p[9]);   pf1.u[1] = pk2(p[10], p[11]);
      pf1.u[2] = pk2(p[12], p[13]); pf1.u[3] = pk2(p[14], p[15]);
      bf16x8 vb00 = *reinterpret_cast<const bf16x8*>(Vb + q * 64 + (hi ^ sx) * 16);
      bf16x8 vb01 = *reinterpret_cast<const bf16x8*>(Vb + q * 64 + ((2 + hi) ^ sx) * 16);
      bf16x8 vb10 = *reinterpret_cast<const bf16x8*>(Vb + (32 + q) * 64 + (hi ^ sx) * 16);
      bf16x8 vb11 = *reinterpret_cast<const bf16x8*>(Vb + (32 + q) * 64 + ((2 + hi) ^ sx) * 16);
      O0 = __builtin_amdgcn_mfma_f32_32x32x16_bf16(vb00, pf0.v, O0, 0, 0, 0);
      O0 = __builtin_amdgcn_mfma_f32_32x32x16_bf16(vb01, pf1.v, O0, 0, 0, 0);
      O1 = __builtin_amdgcn_mfma_f32_32x32x16_bf16(vb10, pf0.v, O1, 0, 0, 0);
      O1 = __builtin_amdgcn_mfma_f32_32x32x16_bf16(vb11, pf1.v, O1, 0, 0, 0);
    }
    __syncthreads();   // drain stage(g+1), sync readers before buf reuse
  }
  float l_run = lacc + __shfl_xor(lacc, 32);

  // -------- wave-final partial dump (reg-major, coalesced) --------
  const int pidx = (bh * 8 + itq) * NJ + jq;
  float* pw = part + (size_t)(pidx * 4 + w) * 34 * 64;
#pragma unroll
  for (int r = 0; r < 16; ++r) pw[r * 64 + l] = O0[r];
#pragma unroll
  for (int r = 0; r < 16; ++r) pw[(16 + r) * 64 + l] = O1[r];
  pw[32 * 64 + l] = m_run;
  pw[33 * 64 + l] = l_run;
}

// ---------------- merge the NJ j-split partials -> aout (bf16) ----------------
template<int NJ>
__global__ void k_fmerge12(const float* __restrict__ part, __bf16* __restrict__ aout) {
  const int u = blockIdx.x;                    // [0,256) = bh*8 + itq
  const int bh = u >> 3, itq = u & 7;
  const int b = bh >> 4, h = bh & 15;
  const int t = threadIdx.x;
  const int w = t >> 6, sub = t & 63, q = sub & 31, hi = sub >> 5;
  const float* pp[NJ];
#pragma unroll
  for (int j = 0; j < NJ; ++j)
    pp[j] = part + (size_t)((u * NJ + j) * 4 + w) * 34 * 64;
  float mm = -INFINITY;
#pragma unroll
  for (int j = 0; j < NJ; ++j) mm = fmaxf(mm, pp[j][32 * 64 + sub]);
  float sc[NJ];
  float ll = 0.f;
#pragma unroll
  for (int j = 0; j < NJ; ++j) {
    sc[j] = fexp2(pp[j][32 * 64 + sub] - mm);
    ll += pp[j][33 * 64 + sub] * sc[j];
  }
  float inv = 1.f / ll;
  const int row = itq * 128 + w * 32 + q;
  __bf16* orow = aout + ((size_t)(b * LATENT) + row) * DIMC + h * DHH;
#pragma unroll
  for (int g = 0; g < 4; ++g) {
    union { __bf16 hh[4]; uint2 u2; } pk;
#pragma unroll
    for (int e = 0; e < 4; ++e) {
      float o = 0.f;
#pragma unroll
      for (int j = 0; j < NJ; ++j) o += pp[j][(4 * g + e) * 64 + sub] * sc[j];
      pk.hh[e] = (__bf16)(o * inv);
    }
    *reinterpret_cast<uint2*>(orow + 8 * g + 4 * hi) = pk.u2;
#pragma unroll
    for (int e = 0; e < 4; ++e) {
      float o = 0.f;
#pragma unroll
      for (int j = 0; j < NJ; ++j) o += pp[j][(16 + 4 * g + e) * 64 + sub] * sc[j];
      pk.hh[e] = (__bf16)(o * inv);
    }
    *reinterpret_cast<uint2*>(orow + 32 + 8 * g + 4 * hi) = pk.u2;
  }
}

// ---------------- host launcher ----------------
extern "C" void kernel_launch(void* const* d_in, const int* in_sizes, int n_in,
                              void* d_out, int out_size, void* d_ws, size_t ws_size,
                              hipStream_t stream) {
  const float* x = (const float*)d_in[0];
  const float* Wq = (const float*)d_in[1];
  const float* Wkv = (const float*)d_in[2];
  const float* Wo = (const float*)d_in[3];
  const float* bo = (const float*)d_in[4];
  const float* gamma = (const float*)d_in[5];
  const float* beta = (const float*)d_in[6];

  char* ws = (char*)d_ws;
  size_t o = 0;
  __bf16* x16 = (__bf16*)(ws + o);  o += (size_t)BATCH * SEQ * DIMC * 2;
  __bf16* wq16 = (__bf16*)(ws + o); o += (size_t)DIMC * DIMC * 2;
  __bf16* wkv16 = (__bf16*)(ws + o); o += (size_t)DIMC * DIMC * 2;
  __bf16* wo16 = (__bf16*)(ws + o); o += (size_t)DIMC * DIMC * 2;
  float2* cstab = (float2*)(ws + o); o += (size_t)SEQ * 32 * 8;
  __bf16* kvn = (__bf16*)(ws + o);  o += (size_t)BATCH * HEADS * SEQ * DHH * 2;
  __bf16* kvnT = (__bf16*)(ws + o); o += (size_t)BATCH * HEADS * SEQ * DHH * 2;
  __bf16* qb = (__bf16*)(ws + o);   o += (size_t)BATCH * HEADS * LATENT * DHH * 2;
  __bf16* aout = (__bf16*)(ws + o); o += (size_t)BATCH * LATENT * DIMC * 2;
  float* part = (float*)(ws + o);   o += (size_t)512 * 4 * 34 * 64 * 4;

  k_prep<<<4096, 256, 0, stream>>>(x, Wq, Wkv, Wo, x16, wq16, wkv16, wo16, cstab);
  k_gemmqkv<<<640, 256, 0, stream>>>(x16, wkv16, wq16, kvn, kvnT, qb, gamma, beta, cstab);
  k_flash12<2><<<512, 256, 0, stream>>>(qb, kvn, kvnT, part);
  k_fmerge12<2><<<256, 256, 0, stream>>>(part, aout);
  k_gemm<1><<<128, 256, 0, stream>>>(aout, wo16, (float*)d_out, bo, 2048, 1024, 1024);
}